// Round 7
// baseline (438.955 us; speedup 1.0000x reference)
//
#include <hip/hip_runtime.h>

#define SEQ_L 1024
#define BATCH_N 512
#define NTAG 48
#define HALF_BLKS 64   // 64 blocks of 8 slots = 512 slots per direction

// NOTE: gfx950 builtins (cvt_pkrtz, fdot2) traffic in __fp16 vectors, not _Float16
typedef __fp16 h2 __attribute__((ext_vector_type(2)));
union H2U { unsigned u; int i; h2 h; };
__device__ inline h2 u_as_h2(unsigned x){ H2U v; v.u = x; return v.h; }
__device__ inline h2 i_as_h2(int x){ H2U v; v.i = x; return v.h; }
__device__ inline int h2_as_i(h2 x){ H2U v; v.h = x; return v.i; }

__device__ inline float wave_sum_f(float v) {
    #pragma unroll
    for (int off = 32; off > 0; off >>= 1) v += __shfl_xor(v, off, 64);
    return v;
}
__device__ inline int wave_sum_i(int v) {
    #pragma unroll
    for (int off = 32; off > 0; off >>= 1) v += __shfl_xor(v, off, 64);
    return v;
}

template <int CTRL>
__device__ inline float dpp_add(float x) {
    int m = __builtin_amdgcn_update_dpp(0, __float_as_int(x), CTRL, 0xF, 0xF, true);
    return x + __int_as_float(m);
}
// lane n gets lane n+1's value within each 16-row (row_shl:1)
__device__ inline float dpp_shl1(float x) {
    int m = __builtin_amdgcn_update_dpp(0, __float_as_int(x), 0x101, 0xF, 0xF, true);
    return __int_as_float(m);
}
__device__ inline float rl_f(float x, int l) {
    return __int_as_float(__builtin_amdgcn_readlane(__float_as_int(x), l));
}

// TRUE sum over lanes 0..47 (row_shr accumulates toward HIGHER lanes:
// after the chain lane 15|31|47 holds its row's full sum).
__device__ inline float psum48(float p) {
    float x = dpp_add<0x111>(p);
    x = dpp_add<0x112>(x);
    x = dpp_add<0x114>(x);
    x = dpp_add<0x118>(x);
    return (rl_f(x, 15) + rl_f(x, 31)) + rl_f(x, 47);
}

#define RLN(v, l) __builtin_amdgcn_readlane((v), (l))
#define FD(j, A)  A = __builtin_amdgcn_fdot2(i_as_h2(s##j), u_as_h2(q##j), A, false);

#define Q24(M) M(0)M(1)M(2)M(3)M(4)M(5)M(6)M(7)M(8)M(9)M(10)M(11)M(12)M(13)M(14)M(15)M(16)M(17)M(18)M(19)M(20)M(21)M(22)M(23)
#define QDECL(j) unsigned q##j; int s##j;
#define QREAD(j) q##j = Ev[(j) * 64 + lane];

#define RLA s0=RLN(pi_,0);  s1=RLN(pi_,2);  s2=RLN(pi_,4);  s3=RLN(pi_,6);  \
            s4=RLN(pi_,8);  s5=RLN(pi_,10); s6=RLN(pi_,12); s7=RLN(pi_,14); \
            s8=RLN(pi_,16); s9=RLN(pi_,18); s10=RLN(pi_,20); s11=RLN(pi_,22);
#define RLB s12=RLN(pi_,24); s13=RLN(pi_,26); s14=RLN(pi_,28); s15=RLN(pi_,30); \
            s16=RLN(pi_,32); s17=RLN(pi_,34); s18=RLN(pi_,36); s19=RLN(pi_,38); \
            s20=RLN(pi_,40); s21=RLN(pi_,42); s22=RLN(pi_,44); s23=RLN(pi_,46);
#define DOTA FD(0,a0) FD(1,a1) FD(2,a2) FD(3,a3) FD(4,a0) FD(5,a1) FD(6,a2) FD(7,a3) FD(8,a0) FD(9,a1) FD(10,a2) FD(11,a3)
#define DOTB FD(12,a0) FD(13,a1) FD(14,a2) FD(15,a3) FD(16,a0) FD(17,a1) FD(18,a2) FD(19,a3) FD(20,a0) FD(21,a1) FD(22,a2) FD(23,a3)

// One scan step, lag-renormalized.
// fwd (FWD=1): p' = (E^T p) * fe_eff     bwd: p' = E (fe_eff o p)
// fe_eff = fe * inv(prev sigma); C += log(prev sigma) iff step applied.
#define STEP1(FWD, FE, MK) {                                                   \
    float fe_ = (FE) * inv;                                                    \
    float src_ = (FWD) ? p : p * fe_;                                          \
    Q24(QDECL)                                                                 \
    Q24(QREAD)                                                                 \
    float nb_ = dpp_shl1(src_);                                                \
    int pi_ = h2_as_i(__builtin_amdgcn_cvt_pkrtz(src_, nb_));                  \
    RLA __builtin_amdgcn_sched_barrier(0);                                     \
    float a0 = 0.f, a1 = 0.f, a2 = 0.f, a3 = 0.f;                              \
    DOTA                                                                       \
    RLB __builtin_amdgcn_sched_barrier(0);                                     \
    DOTB                                                                       \
    float r_ = (a0 + a1) + (a2 + a3);                                          \
    float nxt_ = (FWD) ? r_ * fe_ : r_;                                        \
    p = (MK) ? nxt_ : p;                                                       \
    C += (MK) ? lsg : 0.0f;                                                    \
    float s_ = psum48(p);                                                      \
    inv = __builtin_amdgcn_rcpf(s_);                                           \
    lsg = __logf(s_);                                                          \
}

// prefetch one slot K of block BLK into named scalars e<S><K>/m<S><K>
#define PF1(S,K,BLK,FWD) {                                                     \
    int s_ = (BLK)*8 + (K);                                                    \
    int i_ = (FWD) ? (1+s_) : (1023-s_);                                       \
    bool ok_ = ((BLK) < HALF_BLKS) && ((FWD) ? (s_ < 511) : true);             \
    e##S##K = (act && ok_) ? em[((size_t)i_*BATCH_N + b)*NTAG + lane] : 0.0f;  \
    m##S##K = ok_ ? maskp[i_*BATCH_N + b] : 0; }

#define PF8(S,BLK,FWD)                                                         \
    PF1(S,0,BLK,FWD) PF1(S,1,BLK,FWD) PF1(S,2,BLK,FWD) PF1(S,3,BLK,FWD)        \
    PF1(S,4,BLK,FWD) PF1(S,5,BLK,FWD) PF1(S,6,BLK,FWD) PF1(S,7,BLK,FWD)

// 8 steps, fe exps hoisted off the serial chain
#define STEP8M(FWD,S) {                                                        \
    float f0_=__expf(e##S##0), f1_=__expf(e##S##1);                            \
    float f2_=__expf(e##S##2), f3_=__expf(e##S##3);                            \
    float f4_=__expf(e##S##4), f5_=__expf(e##S##5);                            \
    float f6_=__expf(e##S##6), f7_=__expf(e##S##7);                            \
    STEP1(FWD,f0_,m##S##0) STEP1(FWD,f1_,m##S##1)                              \
    STEP1(FWD,f2_,m##S##2) STEP1(FWD,f3_,m##S##3)                              \
    STEP1(FWD,f4_,m##S##4) STEP1(FWD,f5_,m##S##5)                              \
    STEP1(FWD,f6_,m##S##6) STEP1(FWD,f7_,m##S##7) }

__global__ __launch_bounds__(128, 1) void crf_fwd_kernel(
    const float* __restrict__ em,
    const float* __restrict__ start_t,
    const float* __restrict__ end_t,
    const float* __restrict__ trans,
    const int*   __restrict__ tags,
    const int*   __restrict__ maskp,
    float*       __restrict__ out_per_batch) {
    const int b = blockIdx.x;
    const int tid = threadIdx.x;
    const int w = tid >> 6;          // 0 = forward wave, 1 = backward wave
    const int lane = tid & 63;
    const bool act = lane < NTAG;

    // E packed fp16 pairs in LDS: Epk[w][pair][lane] = (E[2k], E[2k+1]) for this lane.
    // Rows padded to 64 (lanes 48..63 = zeros) -> lane-stride-1 words, 2-way banks = free.
    __shared__ unsigned Epk[2][24][64];
    __shared__ float sh_p[2][NTAG];
    __shared__ float sh_C[2];
    __shared__ float sh_num[2];
    __shared__ int   sh_cnt[2];

    #pragma unroll
    for (int k = 0; k < 24; ++k) {
        float lo = 0.f, hi = 0.f;
        if (act) {
            if (w == 0) { lo = __expf(trans[(2*k)*NTAG + lane]);  hi = __expf(trans[(2*k+1)*NTAG + lane]); }
            else        { lo = __expf(trans[lane*NTAG + 2*k]);    hi = __expf(trans[lane*NTAG + 2*k+1]); }
        }
        Epk[w][k][lane] = (unsigned)h2_as_i(__builtin_amdgcn_cvt_pkrtz(lo, hi));
    }
    const volatile unsigned* Ev = &Epk[w][0][0];   // volatile: keep ds_reads in-loop

    // init state
    float p, C = 0.0f;
    if (w == 0) {
        p = act ? __expf(start_t[lane] + em[(size_t)b * NTAG + lane]) : 0.0f;
    } else {
        p = act ? __expf(end_t[lane]) : 0.0f;
    }
    float sI = psum48(p);
    float inv = __builtin_amdgcn_rcpf(sI);
    float lsg = __logf(sI);

    // named-scalar double-buffer prefetch
    float eA0,eA1,eA2,eA3,eA4,eA5,eA6,eA7;
    float eB0,eB1,eB2,eB3,eB4,eB5,eB6,eB7;
    int   mA0,mA1,mA2,mA3,mA4,mA5,mA6,mA7;
    int   mB0,mB1,mB2,mB3,mB4,mB5,mB6,mB7;

    if (w == 0) {
        PF8(A,0,1) PF8(B,1,1)
        #pragma unroll 1
        for (int blk = 0; blk < HALF_BLKS; blk += 2) {
            STEP8M(1,A) PF8(A,blk+2,1)
            STEP8M(1,B) PF8(B,blk+3,1)
        }
    } else {
        PF8(A,0,0) PF8(B,1,0)
        #pragma unroll 1
        for (int blk = 0; blk < HALF_BLKS; blk += 2) {
            STEP8M(0,A) PF8(A,blk+2,0)
            STEP8M(0,B) PF8(B,blk+3,0)
        }
    }
    // NOTE: final p intentionally NOT divided by its last sigma; C only counts
    // applied divisions, so  true_alpha = p * e^C  exactly.

    // numerator: wave w covers i in [w*512, w*512+511], 64 lanes x 8 iters
    float numpart = 0.0f;
    int cnt = 0;
    #pragma unroll
    for (int j = 0; j < 8; ++j) {
        int i = w * 512 + j * 64 + lane;
        int tag_i = tags[(size_t)i * BATCH_N + b];
        int m = maskp[i * BATCH_N + b];
        cnt += (m != 0);
        if (i == 0) {
            numpart += start_t[tag_i] + em[(size_t)b * NTAG + tag_i];
        } else if (m) {
            int tag_p = tags[(size_t)(i - 1) * BATCH_N + b];
            numpart += trans[tag_p * NTAG + tag_i] +
                       em[((size_t)i * BATCH_N + b) * NTAG + tag_i];
        }
    }
    float num = wave_sum_f(numpart);
    int cnth = wave_sum_i(cnt);

    // exchange via LDS, combine halves:  Z = sum_t p_fwd[t] * u_bwd[t] * e^(Cf+Cb)
    if (act) sh_p[w][lane] = p;
    if (lane == 0) { sh_C[w] = C; sh_num[w] = num; sh_cnt[w] = cnth; }
    __syncthreads();

    if (w == 0) {
        float dot = act ? p * sh_p[1][lane] : 0.0f;
        float zs = wave_sum_f(dot);
        float log_z = sh_C[0] + sh_C[1] + __logf(zs);
        int seq_len = sh_cnt[0] + sh_cnt[1];
        int last_tag = tags[(size_t)(seq_len - 1) * BATCH_N + b];
        float num_tot = sh_num[0] + sh_num[1] + end_t[last_tag];
        if (lane == 0) out_per_batch[b] = log_z - num_tot;   // = -llh[b]
    }
}

__global__ __launch_bounds__(512) void reduce512_kernel(
    const float* __restrict__ v, float* __restrict__ out) {
    float x = v[threadIdx.x];
    x = wave_sum_f(x);
    __shared__ float ws[8];
    int w = threadIdx.x >> 6;
    if ((threadIdx.x & 63) == 0) ws[w] = x;
    __syncthreads();
    if (threadIdx.x == 0) {
        float t = 0.0f;
        #pragma unroll
        for (int k = 0; k < 8; ++k) t += ws[k];
        *out = t;
    }
}

extern "C" void kernel_launch(void* const* d_in, const int* in_sizes, int n_in,
                              void* d_out, int out_size, void* d_ws, size_t ws_size,
                              hipStream_t stream) {
    const float* emissions = (const float*)d_in[0];
    const float* start_t   = (const float*)d_in[1];
    const float* end_t     = (const float*)d_in[2];
    const float* trans     = (const float*)d_in[3];
    const int*   tags      = (const int*)d_in[4];
    const int*   mask      = (const int*)d_in[5];
    float* per_batch = (float*)d_ws;

    crf_fwd_kernel<<<BATCH_N, 128, 0, stream>>>(emissions, start_t, end_t, trans,
                                                tags, mask, per_batch);
    reduce512_kernel<<<1, 512, 0, stream>>>(per_batch, (float*)d_out);
}

// Round 8
// 296.354 us; speedup vs baseline: 1.4812x; 1.4812x over previous
//
#include <hip/hip_runtime.h>

#define SEQ_L 1024
#define BATCH_N 512
#define NTAG 48
#define HALF_BLKS 64   // 64 blocks of 8 slots = 512 slots per direction

__device__ inline float wave_sum_f(float v) {
    #pragma unroll
    for (int off = 32; off > 0; off >>= 1) v += __shfl_xor(v, off, 64);
    return v;
}
__device__ inline int wave_sum_i(int v) {
    #pragma unroll
    for (int off = 32; off > 0; off >>= 1) v += __shfl_xor(v, off, 64);
    return v;
}

// x += (x shifted right by K lanes within each 16-lane row), via DPP (VALU pipe)
template <int CTRL>
__device__ inline float dpp_add(float x) {
    int m = __builtin_amdgcn_update_dpp(0, __float_as_int(x), CTRL, 0xF, 0xF, true);
    return x + __int_as_float(m);
}
__device__ inline float rl_f(float x, int l) {
    return __int_as_float(__builtin_amdgcn_readlane(__float_as_int(x), l));
}

// TRUE sum over lanes 0..47 (row_shr accumulates toward higher lanes:
// lane 15|31|47 ends with its 16-row's full sum).
__device__ inline float psum48(float p) {
    float x = dpp_add<0x111>(p);
    x = dpp_add<0x112>(x);
    x = dpp_add<0x114>(x);
    x = dpp_add<0x118>(x);
    return (rl_f(x, 15) + rl_f(x, 31)) + rl_f(x, 47);
}

#define RLF(si, L) __int_as_float(__builtin_amdgcn_readlane((si), L))

// one 12-wide group: 12 independent readlanes, then 12 FMAs (SGPRs aged >=24cyc)
#define MVG(si,T0,T1,T2,T3,T4,T5,T6,T7,T8,T9,T10,T11)                          \
    s0=RLF(si,T0); s1=RLF(si,T1); s2=RLF(si,T2); s3=RLF(si,T3);                \
    s4=RLF(si,T4); s5=RLF(si,T5); s6=RLF(si,T6); s7=RLF(si,T7);                \
    s8=RLF(si,T8); s9=RLF(si,T9); s10=RLF(si,T10); s11=RLF(si,T11);            \
    __builtin_amdgcn_sched_barrier(0);                                         \
    a0=fmaf(s0,E##T0,a0); a1=fmaf(s1,E##T1,a1); a2=fmaf(s2,E##T2,a2); a3=fmaf(s3,E##T3,a3); \
    a0=fmaf(s4,E##T4,a0); a1=fmaf(s5,E##T5,a1); a2=fmaf(s6,E##T6,a2); a3=fmaf(s7,E##T7,a3); \
    a0=fmaf(s8,E##T8,a0); a1=fmaf(s9,E##T9,a1); a2=fmaf(s10,E##T10,a2); a3=fmaf(s11,E##T11,a3); \
    __builtin_amdgcn_sched_barrier(0);

// dst[lane] = sum_t src[t] * E_t   (48-way broadcast matvec, all in registers)
#define MATVEC48(dst, si) {                                                    \
    float a0=0.f,a1=0.f,a2=0.f,a3=0.f;                                         \
    float s0,s1,s2,s3,s4,s5,s6,s7,s8,s9,s10,s11;                               \
    MVG(si,0,1,2,3,4,5,6,7,8,9,10,11)                                          \
    MVG(si,12,13,14,15,16,17,18,19,20,21,22,23)                                \
    MVG(si,24,25,26,27,28,29,30,31,32,33,34,35)                                \
    MVG(si,36,37,38,39,40,41,42,43,44,45,46,47)                                \
    dst = (a0+a1)+(a2+a3); }

// prefetch one slot K of block BLK: emission into e<S><K>, mask into bit K of m<S>
#define PF1(S,K,BLK,FWD) {                                                     \
    int s_ = (BLK)*8 + (K);                                                    \
    int i_ = (FWD) ? (1+s_) : (1023-s_);                                       \
    bool ok_ = ((BLK) < HALF_BLKS) && ((FWD) ? (s_ < 511) : true);             \
    e##S##K = (act && ok_) ? em[((size_t)i_*BATCH_N + b)*NTAG + lane] : 0.0f;  \
    if (ok_ && maskp[i_*BATCH_N + b]) m##S |= (1 << (K)); }

#define PF8(S,BLK,FWD) m##S = 0;                                               \
    PF1(S,0,BLK,FWD) PF1(S,1,BLK,FWD) PF1(S,2,BLK,FWD) PF1(S,3,BLK,FWD)        \
    PF1(S,4,BLK,FWD) PF1(S,5,BLK,FWD) PF1(S,6,BLK,FWD) PF1(S,7,BLK,FWD)

// one scan step.  fwd: p' = (E^T p)*fe    bwd: p' = E (fe o p)
#define STEP1(FWD,FE,MKBIT) {                                                  \
    float src_ = (FWD) ? p : p*(FE);                                           \
    int si_ = __float_as_int(src_);                                            \
    float r_; MATVEC48(r_, si_)                                                \
    float nxt_ = (FWD) ? r_*(FE) : r_;                                         \
    p = (MKBIT) ? nxt_ : p; }

// 8 steps + one renormalization (exp's hoisted off the serial chain)
#define STEP8M(FWD,S) {                                                        \
    float f0_=__expf(e##S##0), f1_=__expf(e##S##1);                            \
    float f2_=__expf(e##S##2), f3_=__expf(e##S##3);                            \
    float f4_=__expf(e##S##4), f5_=__expf(e##S##5);                            \
    float f6_=__expf(e##S##6), f7_=__expf(e##S##7);                            \
    STEP1(FWD,f0_,(m##S)&1)      STEP1(FWD,f1_,(m##S>>1)&1)                    \
    STEP1(FWD,f2_,(m##S>>2)&1)   STEP1(FWD,f3_,(m##S>>3)&1)                    \
    STEP1(FWD,f4_,(m##S>>4)&1)   STEP1(FWD,f5_,(m##S>>5)&1)                    \
    STEP1(FWD,f6_,(m##S>>6)&1)   STEP1(FWD,f7_,(m##S>>7)&1)                    \
    float sum_ = psum48(p);                                                    \
    C += __logf(sum_);                                                         \
    p *= __builtin_amdgcn_rcpf(sum_); }

#define REP48(M) M(0)M(1)M(2)M(3)M(4)M(5)M(6)M(7)M(8)M(9)M(10)M(11)M(12)M(13)M(14)M(15)M(16)M(17)M(18)M(19)M(20)M(21)M(22)M(23)M(24)M(25)M(26)M(27)M(28)M(29)M(30)M(31)M(32)M(33)M(34)M(35)M(36)M(37)M(38)M(39)M(40)M(41)M(42)M(43)M(44)M(45)M(46)M(47)

#define EDECL(t) float E##t;
#define EINIT(t) E##t = act ? __expf(trans[(t)*rs + lane*cs]) : 0.0f;

// amdgpu_waves_per_eu(1,2): VGPR budget for 1-wave/EU (512) -> E stays in registers.
__attribute__((amdgpu_flat_work_group_size(128,128), amdgpu_waves_per_eu(1,2)))
__global__ void crf_fwd_kernel(
    const float* __restrict__ em,
    const float* __restrict__ start_t,
    const float* __restrict__ end_t,
    const float* __restrict__ trans,
    const int*   __restrict__ tags,
    const int*   __restrict__ maskp,
    float*       __restrict__ out_per_batch) {
    const int b = blockIdx.x;
    const int tid = threadIdx.x;
    const int w = tid >> 6;          // 0 = forward wave, 1 = backward wave
    const int lane = tid & 63;
    const bool act = lane < NTAG;

    __shared__ float sh_p[2][NTAG];
    __shared__ float sh_C[2];
    __shared__ float sh_num[2];
    __shared__ int   sh_cnt[2];

    // E fragment in 48 NAMED scalars.
    // fwd (w=0): E_t = exp(trans[t][lane]) (column); bwd: exp(trans[lane][t]) (row)
    const int rs = (w == 0) ? NTAG : 1;
    const int cs = (w == 0) ? 1 : NTAG;
    REP48(EDECL)
    REP48(EINIT)

    // init state
    float p, C = 0.0f;
    if (w == 0) {
        p = act ? __expf(start_t[lane] + em[(size_t)b * NTAG + lane]) : 0.0f;
    } else {
        p = act ? __expf(end_t[lane]) : 0.0f;
    }

    // double-buffered named-scalar prefetch (masks bit-packed: 1 int per 8 slots)
    float eA0,eA1,eA2,eA3,eA4,eA5,eA6,eA7;
    float eB0,eB1,eB2,eB3,eB4,eB5,eB6,eB7;
    int   mA, mB;

    if (w == 0) {
        PF8(A,0,1) PF8(B,1,1)
        #pragma unroll 1
        for (int blk = 0; blk < HALF_BLKS; blk += 2) {
            STEP8M(1,A) PF8(A,blk+2,1)
            STEP8M(1,B) PF8(B,blk+3,1)
        }
    } else {
        PF8(A,0,0) PF8(B,1,0)
        #pragma unroll 1
        for (int blk = 0; blk < HALF_BLKS; blk += 2) {
            STEP8M(0,A) PF8(A,blk+2,0)
            STEP8M(0,B) PF8(B,blk+3,0)
        }
    }

    // numerator: wave w covers i in [w*512, w*512+511], 64 lanes x 8 iters
    float numpart = 0.0f;
    int cnt = 0;
    #pragma unroll
    for (int j = 0; j < 8; ++j) {
        int i = w * 512 + j * 64 + lane;
        int tag_i = tags[(size_t)i * BATCH_N + b];
        int m = maskp[i * BATCH_N + b];
        cnt += (m != 0);
        if (i == 0) {
            numpart += start_t[tag_i] + em[(size_t)b * NTAG + tag_i];
        } else if (m) {
            int tag_p = tags[(size_t)(i - 1) * BATCH_N + b];
            numpart += trans[tag_p * NTAG + tag_i] +
                       em[((size_t)i * BATCH_N + b) * NTAG + tag_i];
        }
    }
    float num = wave_sum_f(numpart);
    int cnth = wave_sum_i(cnt);

    // exchange via LDS, combine halves:  Z = sum_t p_fwd[t] * u_bwd[t] * e^(Cf+Cb)
    if (act) sh_p[w][lane] = p;
    if (lane == 0) { sh_C[w] = C; sh_num[w] = num; sh_cnt[w] = cnth; }
    __syncthreads();

    if (w == 0) {
        float dot = act ? p * sh_p[1][lane] : 0.0f;
        float zs = wave_sum_f(dot);
        float log_z = sh_C[0] + sh_C[1] + __logf(zs);
        int seq_len = sh_cnt[0] + sh_cnt[1];
        int last_tag = tags[(size_t)(seq_len - 1) * BATCH_N + b];
        float num_tot = sh_num[0] + sh_num[1] + end_t[last_tag];
        if (lane == 0) out_per_batch[b] = log_z - num_tot;   // = -llh[b]
    }
}

__global__ __launch_bounds__(512) void reduce512_kernel(
    const float* __restrict__ v, float* __restrict__ out) {
    float x = v[threadIdx.x];
    x = wave_sum_f(x);
    __shared__ float ws[8];
    int w = threadIdx.x >> 6;
    if ((threadIdx.x & 63) == 0) ws[w] = x;
    __syncthreads();
    if (threadIdx.x == 0) {
        float t = 0.0f;
        #pragma unroll
        for (int k = 0; k < 8; ++k) t += ws[k];
        *out = t;
    }
}

extern "C" void kernel_launch(void* const* d_in, const int* in_sizes, int n_in,
                              void* d_out, int out_size, void* d_ws, size_t ws_size,
                              hipStream_t stream) {
    const float* emissions = (const float*)d_in[0];
    const float* start_t   = (const float*)d_in[1];
    const float* end_t     = (const float*)d_in[2];
    const float* trans     = (const float*)d_in[3];
    const int*   tags      = (const int*)d_in[4];
    const int*   mask      = (const int*)d_in[5];
    float* per_batch = (float*)d_ws;

    crf_fwd_kernel<<<BATCH_N, 128, 0, stream>>>(emissions, start_t, end_t, trans,
                                                tags, mask, per_batch);
    reduce512_kernel<<<1, 512, 0, stream>>>(per_batch, (float*)d_out);
}

// Round 9
// 199.840 us; speedup vs baseline: 2.1965x; 1.4830x over previous
//
#include <hip/hip_runtime.h>

#define SEQ_L 1024
#define BATCH_N 512
#define NTAG 48

typedef __fp16 h2v __attribute__((ext_vector_type(2)));
typedef __fp16 h4v __attribute__((ext_vector_type(4)));
typedef float f4v __attribute__((ext_vector_type(4)));

__device__ inline h4v pk4(float a, float b, float c, float d) {
    h2v lo = __builtin_amdgcn_cvt_pkrtz(a, b);
    h2v hi = __builtin_amdgcn_cvt_pkrtz(c, d);
    return __builtin_shufflevector(lo, hi, 0, 1, 2, 3);
}

__device__ inline float wave_sum_f(float v) {
    #pragma unroll
    for (int off = 32; off > 0; off >>= 1) v += __shfl_xor(v, off, 64);
    return v;
}
__device__ inline int wave_sum_i(int v) {
    #pragma unroll
    for (int off = 32; off > 0; off >>= 1) v += __shfl_xor(v, off, 64);
    return v;
}

// column-sum across the 4 row-groups (state is X[t, b]: col b = lane&15)
__device__ inline float colsum4(float part) {
    part += __shfl_xor(part, 16, 64);
    part += __shfl_xor(part, 32, 64);
    return part;
}

#define MFMA16 __builtin_amdgcn_mfma_f32_16x16x16f16

// ---- prefetch macros: 4 named buffers, each {3 x float4 emissions, 1 mask}
#define PFDECL(B) f4v p##B##e0, p##B##e1, p##B##e2; int p##B##m;
#define PF(B, IT) {                                                            \
    int it2_ = (IT) > 511 ? 511 : (IT);                                        \
    int idx_ = fwd ? it2_ : (1023 - it2_);                                     \
    const float* p_ = em + (size_t)idx_ * (BATCH_N * NTAG) + laneoff;          \
    p##B##e0 = *(const f4v*)(p_);                                              \
    p##B##e1 = *(const f4v*)(p_ + 16);                                         \
    p##B##e2 = *(const f4v*)(p_ + 32);                                         \
    int m_ = maskp[idx_ * BATCH_N + bb + c];                                   \
    p##B##m = (fwd && idx_ == 0) ? 0 : m_;                                     \
}

// fwd step: C = E^T X (MFMA), X' = C.F, renorm cols, repack into B-frags
#define STEP_F(B) {                                                            \
    f4v F0, F1, F2;                                                            \
    _Pragma("unroll") for (int j = 0; j < 4; ++j) {                            \
        F0[j] = __expf(p##B##e0[j]);                                           \
        F1[j] = __expf(p##B##e1[j]);                                           \
        F2[j] = __expf(p##B##e2[j]);                                           \
    }                                                                          \
    f4v C0 = MFMA16(A00, Bf0, kz, 0, 0, 0);                                    \
    C0 = MFMA16(A01, Bf1, C0, 0, 0, 0);                                        \
    C0 = MFMA16(A02, Bf2, C0, 0, 0, 0);                                        \
    f4v C1 = MFMA16(A10, Bf0, kz, 0, 0, 0);                                    \
    C1 = MFMA16(A11, Bf1, C1, 0, 0, 0);                                        \
    C1 = MFMA16(A12, Bf2, C1, 0, 0, 0);                                        \
    f4v C2 = MFMA16(A20, Bf0, kz, 0, 0, 0);                                    \
    C2 = MFMA16(A21, Bf1, C2, 0, 0, 0);                                        \
    C2 = MFMA16(A22, Bf2, C2, 0, 0, 0);                                        \
    f4v X0 = C0 * F0, X1 = C1 * F1, X2 = C2 * F2;                              \
    float part_ = ((X0[0] + X0[1]) + (X0[2] + X0[3]))                          \
                + ((X1[0] + X1[1]) + (X1[2] + X1[3]))                          \
                + ((X2[0] + X2[1]) + (X2[2] + X2[3]));                         \
    float s_ = colsum4(part_);                                                 \
    float inv_ = __builtin_amdgcn_rcpf(s_);                                    \
    h4v n0_ = pk4(X0[0]*inv_, X0[1]*inv_, X0[2]*inv_, X0[3]*inv_);             \
    h4v n1_ = pk4(X1[0]*inv_, X1[1]*inv_, X1[2]*inv_, X1[3]*inv_);             \
    h4v n2_ = pk4(X2[0]*inv_, X2[1]*inv_, X2[2]*inv_, X2[3]*inv_);             \
    bool mk_ = p##B##m != 0;                                                   \
    Bf0 = mk_ ? n0_ : Bf0;                                                     \
    Bf1 = mk_ ? n1_ : Bf1;                                                     \
    Bf2 = mk_ ? n2_ : Bf2;                                                     \
    ls += mk_ ? __logf(s_) : 0.0f;                                             \
}

// bwd step: Y = S.F, renorm, pack, S' = E Y (MFMA), masked select
#define STEP_B(B) {                                                            \
    f4v F0, F1, F2;                                                            \
    _Pragma("unroll") for (int j = 0; j < 4; ++j) {                            \
        F0[j] = __expf(p##B##e0[j]);                                           \
        F1[j] = __expf(p##B##e1[j]);                                           \
        F2[j] = __expf(p##B##e2[j]);                                           \
    }                                                                          \
    f4v Y0 = S0 * F0, Y1 = S1 * F1, Y2 = S2 * F2;                              \
    float part_ = ((Y0[0] + Y0[1]) + (Y0[2] + Y0[3]))                          \
                + ((Y1[0] + Y1[1]) + (Y1[2] + Y1[3]))                          \
                + ((Y2[0] + Y2[1]) + (Y2[2] + Y2[3]));                         \
    float s_ = colsum4(part_);                                                 \
    float inv_ = __builtin_amdgcn_rcpf(s_);                                    \
    h4v b0_ = pk4(Y0[0]*inv_, Y0[1]*inv_, Y0[2]*inv_, Y0[3]*inv_);             \
    h4v b1_ = pk4(Y1[0]*inv_, Y1[1]*inv_, Y1[2]*inv_, Y1[3]*inv_);             \
    h4v b2_ = pk4(Y2[0]*inv_, Y2[1]*inv_, Y2[2]*inv_, Y2[3]*inv_);             \
    f4v C0 = MFMA16(A00, b0_, kz, 0, 0, 0);                                    \
    C0 = MFMA16(A01, b1_, C0, 0, 0, 0);                                        \
    C0 = MFMA16(A02, b2_, C0, 0, 0, 0);                                        \
    f4v C1 = MFMA16(A10, b0_, kz, 0, 0, 0);                                    \
    C1 = MFMA16(A11, b1_, C1, 0, 0, 0);                                        \
    C1 = MFMA16(A12, b2_, C1, 0, 0, 0);                                        \
    f4v C2 = MFMA16(A20, b0_, kz, 0, 0, 0);                                    \
    C2 = MFMA16(A21, b1_, C2, 0, 0, 0);                                        \
    C2 = MFMA16(A22, b2_, C2, 0, 0, 0);                                        \
    bool mk_ = p##B##m != 0;                                                   \
    S0 = mk_ ? C0 : S0;                                                        \
    S1 = mk_ ? C1 : S1;                                                        \
    S2 = mk_ ? C2 : S2;                                                        \
    ls += mk_ ? __logf(s_) : 0.0f;                                             \
}

__global__ __launch_bounds__(128, 1) void crf_scan_kernel(
    const float* __restrict__ em,
    const float* __restrict__ start_t,
    const float* __restrict__ end_t,
    const float* __restrict__ trans,
    const int*   __restrict__ maskp,
    float*       __restrict__ z_out) {
    const int bb = blockIdx.x * 16;        // batch tile base
    const int w = threadIdx.x >> 6;        // 0 = fwd wave, 1 = bwd wave
    const bool fwd = (w == 0);
    const int lane = threadIdx.x & 63;
    const int c = lane & 15;               // batch column
    const int g = lane >> 4;               // row group

    __shared__ float shX[NTAG][17];
    __shared__ float shL[16];

    // ---- constant A fragments: fwd A=E^T (A[t'][t]=exp(trans[t][t'])),
    //      bwd A=E (A[t][t']=exp(trans[t][t'])).  k = 16*kt + 4*g + j.
    h4v A00, A01, A02, A10, A11, A12, A20, A21, A22;
    {
        #define LOADA(MT, KT, DST) {                                           \
            float e_[4];                                                       \
            _Pragma("unroll") for (int j = 0; j < 4; ++j) {                    \
                int kidx_ = 16*(KT) + 4*g + j;                                 \
                int midx_ = 16*(MT) + c;                                       \
                int r_ = fwd ? kidx_ : midx_;                                  \
                int cc_ = fwd ? midx_ : kidx_;                                 \
                e_[j] = __expf(trans[r_ * NTAG + cc_]);                        \
            }                                                                  \
            DST = pk4(e_[0], e_[1], e_[2], e_[3]);                             \
        }
        LOADA(0,0,A00) LOADA(0,1,A01) LOADA(0,2,A02)
        LOADA(1,0,A10) LOADA(1,1,A11) LOADA(1,2,A12)
        LOADA(2,0,A20) LOADA(2,1,A21) LOADA(2,2,A22)
        #undef LOADA
    }

    const f4v kz = {0.f, 0.f, 0.f, 0.f};
    const size_t laneoff = (size_t)(bb + c) * NTAG + (size_t)g * 4;

    // ---- state init
    h4v Bf0, Bf1, Bf2;        // fwd state: X as B-fragments (fp16, col-normalized)
    f4v S0, S1, S2;           // bwd state (f32 C-layout)
    float ls = 0.0f;          // accumulated log-scale

    if (fwd) {
        f4v X0, X1, X2;
        f4v e0 = *(const f4v*)(em + laneoff);
        f4v e1 = *(const f4v*)(em + laneoff + 16);
        f4v e2 = *(const f4v*)(em + laneoff + 32);
        #pragma unroll
        for (int j = 0; j < 4; ++j) {
            X0[j] = __expf(start_t[ 0 + 4*g + j] + e0[j]);
            X1[j] = __expf(start_t[16 + 4*g + j] + e1[j]);
            X2[j] = __expf(start_t[32 + 4*g + j] + e2[j]);
        }
        float part = ((X0[0]+X0[1])+(X0[2]+X0[3])) + ((X1[0]+X1[1])+(X1[2]+X1[3]))
                   + ((X2[0]+X2[1])+(X2[2]+X2[3]));
        float s = colsum4(part);
        float inv = __builtin_amdgcn_rcpf(s);
        ls = __logf(s);
        Bf0 = pk4(X0[0]*inv, X0[1]*inv, X0[2]*inv, X0[3]*inv);
        Bf1 = pk4(X1[0]*inv, X1[1]*inv, X1[2]*inv, X1[3]*inv);
        Bf2 = pk4(X2[0]*inv, X2[1]*inv, X2[2]*inv, X2[3]*inv);
    } else {
        #pragma unroll
        for (int j = 0; j < 4; ++j) {
            S0[j] = __expf(end_t[ 0 + 4*g + j]);
            S1[j] = __expf(end_t[16 + 4*g + j]);
            S2[j] = __expf(end_t[32 + 4*g + j]);
        }
    }

    // ---- main scan: 512 iterations, 4-deep prefetch
    PFDECL(0) PFDECL(1) PFDECL(2) PFDECL(3)
    PF(0, 0) PF(1, 1) PF(2, 2) PF(3, 3)
    if (fwd) {
        #pragma unroll 1
        for (int i = 0; i < 512; i += 4) {
            STEP_F(0) PF(0, i + 4)
            STEP_F(1) PF(1, i + 5)
            STEP_F(2) PF(2, i + 6)
            STEP_F(3) PF(3, i + 7)
        }
    } else {
        #pragma unroll 1
        for (int i = 0; i < 512; i += 4) {
            STEP_B(0) PF(0, i + 4)
            STEP_B(1) PF(1, i + 5)
            STEP_B(2) PF(2, i + 6)
            STEP_B(3) PF(3, i + 7)
        }
    }

    // ---- combine:  logZ_b = lsF + lsB + log( sum_t X[t,b] * U[t,b] )
    if (fwd) {
        #pragma unroll
        for (int j = 0; j < 4; ++j) {
            shX[ 0 + 4*g + j][c] = (float)Bf0[j];
            shX[16 + 4*g + j][c] = (float)Bf1[j];
            shX[32 + 4*g + j][c] = (float)Bf2[j];
        }
        if (lane < 16) shL[lane] = ls;
    }
    __syncthreads();
    if (!fwd) {
        float d = 0.f;
        #pragma unroll
        for (int j = 0; j < 4; ++j) {
            d += S0[j] * shX[ 0 + 4*g + j][c];
            d += S1[j] * shX[16 + 4*g + j][c];
            d += S2[j] * shX[32 + 4*g + j][c];
        }
        d = colsum4(d);
        float logz = shL[c] + ls + __logf(d);
        if (lane < 16) z_out[bb + lane] = logz;
    }
}

__global__ __launch_bounds__(64) void crf_num_kernel(
    const float* __restrict__ em,
    const float* __restrict__ start_t,
    const float* __restrict__ end_t,
    const float* __restrict__ trans,
    const int*   __restrict__ tags,
    const int*   __restrict__ maskp,
    float*       __restrict__ num_out) {
    const int b = blockIdx.x;
    const int lane = threadIdx.x;
    float numpart = 0.0f;
    int cnt = 0;
    #pragma unroll 4
    for (int jj = 0; jj < 16; ++jj) {
        int i = jj * 64 + lane;
        int tag_i = tags[(size_t)i * BATCH_N + b];
        int m = maskp[i * BATCH_N + b];
        cnt += (m != 0);
        if (i == 0) {
            numpart += start_t[tag_i] + em[(size_t)b * NTAG + tag_i];
        } else if (m) {
            int tag_p = tags[(size_t)(i - 1) * BATCH_N + b];
            numpart += trans[tag_p * NTAG + tag_i] +
                       em[((size_t)i * BATCH_N + b) * NTAG + tag_i];
        }
    }
    float num = wave_sum_f(numpart);
    int seq_len = wave_sum_i(cnt);
    int last_tag = tags[(size_t)(seq_len - 1) * BATCH_N + b];
    if (lane == 0) num_out[b] = num + end_t[last_tag];
}

__global__ __launch_bounds__(512) void final_reduce_kernel(
    const float* __restrict__ z, const float* __restrict__ num,
    float* __restrict__ out) {
    float x = z[threadIdx.x] - num[threadIdx.x];   // = -llh[b]
    x = wave_sum_f(x);
    __shared__ float ws[8];
    int w = threadIdx.x >> 6;
    if ((threadIdx.x & 63) == 0) ws[w] = x;
    __syncthreads();
    if (threadIdx.x == 0) {
        float t = 0.0f;
        #pragma unroll
        for (int k = 0; k < 8; ++k) t += ws[k];
        *out = t;
    }
}

extern "C" void kernel_launch(void* const* d_in, const int* in_sizes, int n_in,
                              void* d_out, int out_size, void* d_ws, size_t ws_size,
                              hipStream_t stream) {
    const float* emissions = (const float*)d_in[0];
    const float* start_t   = (const float*)d_in[1];
    const float* end_t     = (const float*)d_in[2];
    const float* trans     = (const float*)d_in[3];
    const int*   tags      = (const int*)d_in[4];
    const int*   mask      = (const int*)d_in[5];
    float* z_ws   = (float*)d_ws;            // [512]
    float* num_ws = z_ws + BATCH_N;          // [512]

    crf_scan_kernel<<<BATCH_N / 16, 128, 0, stream>>>(emissions, start_t, end_t,
                                                      trans, mask, z_ws);
    crf_num_kernel<<<BATCH_N, 64, 0, stream>>>(emissions, start_t, end_t, trans,
                                               tags, mask, num_ws);
    final_reduce_kernel<<<1, 512, 0, stream>>>(z_ws, num_ws, (float*)d_out);
}

// Round 10
// 170.905 us; speedup vs baseline: 2.5684x; 1.1693x over previous
//
#include <hip/hip_runtime.h>

#define SEQ_L 1024
#define BATCH_N 512
#define NTAG 48

typedef __fp16 h2v __attribute__((ext_vector_type(2)));
typedef __fp16 h4v __attribute__((ext_vector_type(4)));
typedef float f4v __attribute__((ext_vector_type(4)));

__device__ inline h4v pk4(float a, float b, float c, float d) {
    h2v lo = __builtin_amdgcn_cvt_pkrtz(a, b);
    h2v hi = __builtin_amdgcn_cvt_pkrtz(c, d);
    return __builtin_shufflevector(lo, hi, 0, 1, 2, 3);
}

__device__ inline float wave_sum_f(float v) {
    #pragma unroll
    for (int off = 32; off > 0; off >>= 1) v += __shfl_xor(v, off, 64);
    return v;
}
__device__ inline int wave_sum_i(int v) {
    #pragma unroll
    for (int off = 32; off > 0; off >>= 1) v += __shfl_xor(v, off, 64);
    return v;
}

// column-sum across the 4 row-groups (cold path only)
__device__ inline float colsum4(float part) {
    part += __shfl_xor(part, 16, 64);
    part += __shfl_xor(part, 32, 64);
    return part;
}

#define MFMA16 __builtin_amdgcn_mfma_f32_16x16x16f16

// ---- prefetch: 4 named buffers, each {3 x float4 emissions, 1 mask}
#define PFDECL(B) f4v p##B##e0, p##B##e1, p##B##e2; int p##B##m;
#define PF(B, IT) {                                                            \
    int it2_ = (IT) > 511 ? 511 : (IT);                                        \
    int idx_ = fwd ? it2_ : (1023 - it2_);                                     \
    const float* p_ = em + (size_t)idx_ * (BATCH_N * NTAG) + laneoff;          \
    p##B##e0 = *(const f4v*)(p_);                                              \
    p##B##e1 = *(const f4v*)(p_ + 16);                                         \
    p##B##e2 = *(const f4v*)(p_ + 32);                                         \
    int m_ = maskp[idx_ * BATCH_N + bb + c];                                   \
    p##B##m = (fwd && idx_ == 0) ? 0 : m_;                                     \
}

// fwd step: C = E^T X (MFMA), Cs = colsum(C) via A4 (MFMA), X' = C.F/Cs
// invariant: alpha = X_hat * e^ls   (X_hat fp16, entries <= maxF)
#define STEP_F(B) {                                                            \
    f4v F0, F1, F2;                                                            \
    _Pragma("unroll") for (int j = 0; j < 4; ++j) {                            \
        F0[j] = __expf(p##B##e0[j]);                                           \
        F1[j] = __expf(p##B##e1[j]);                                           \
        F2[j] = __expf(p##B##e2[j]);                                           \
    }                                                                          \
    f4v Cs = MFMA16(A40, Bf0, kz, 0, 0, 0);                                    \
    Cs = MFMA16(A41, Bf1, Cs, 0, 0, 0);                                        \
    Cs = MFMA16(A42, Bf2, Cs, 0, 0, 0);                                        \
    f4v C0 = MFMA16(A00, Bf0, kz, 0, 0, 0);                                    \
    C0 = MFMA16(A01, Bf1, C0, 0, 0, 0);                                        \
    C0 = MFMA16(A02, Bf2, C0, 0, 0, 0);                                        \
    f4v C1 = MFMA16(A10, Bf0, kz, 0, 0, 0);                                    \
    C1 = MFMA16(A11, Bf1, C1, 0, 0, 0);                                        \
    C1 = MFMA16(A12, Bf2, C1, 0, 0, 0);                                        \
    f4v C2 = MFMA16(A20, Bf0, kz, 0, 0, 0);                                    \
    C2 = MFMA16(A21, Bf1, C2, 0, 0, 0);                                        \
    C2 = MFMA16(A22, Bf2, C2, 0, 0, 0);                                        \
    float inv_ = __builtin_amdgcn_rcpf(Cs[0]);                                 \
    f4v W0 = F0 * inv_, W1 = F1 * inv_, W2 = F2 * inv_;                        \
    f4v X0 = C0 * W0, X1 = C1 * W1, X2 = C2 * W2;                              \
    h4v n0_ = pk4(X0[0], X0[1], X0[2], X0[3]);                                 \
    h4v n1_ = pk4(X1[0], X1[1], X1[2], X1[3]);                                 \
    h4v n2_ = pk4(X2[0], X2[1], X2[2], X2[3]);                                 \
    bool mk_ = p##B##m != 0;                                                   \
    Bf0 = mk_ ? n0_ : Bf0;                                                     \
    Bf1 = mk_ ? n1_ : Bf1;                                                     \
    Bf2 = mk_ ? n2_ : Bf2;                                                     \
    ls += mk_ ? __logf(Cs[0]) : 0.0f;                                          \
}

// bwd step: Y = S.F*inv_pending, pack, S' = E Y, Cs = colsum(S') via A4
// invariant: u = S * inv * e^ls
#define STEP_B(B) {                                                            \
    f4v F0, F1, F2;                                                            \
    _Pragma("unroll") for (int j = 0; j < 4; ++j) {                            \
        F0[j] = __expf(p##B##e0[j]);                                           \
        F1[j] = __expf(p##B##e1[j]);                                           \
        F2[j] = __expf(p##B##e2[j]);                                           \
    }                                                                          \
    f4v W0 = F0 * inv, W1 = F1 * inv, W2 = F2 * inv;                           \
    f4v Y0 = S0 * W0, Y1 = S1 * W1, Y2 = S2 * W2;                              \
    h4v b0_ = pk4(Y0[0], Y0[1], Y0[2], Y0[3]);                                 \
    h4v b1_ = pk4(Y1[0], Y1[1], Y1[2], Y1[3]);                                 \
    h4v b2_ = pk4(Y2[0], Y2[1], Y2[2], Y2[3]);                                 \
    f4v Cs = MFMA16(A40, b0_, kz, 0, 0, 0);                                    \
    Cs = MFMA16(A41, b1_, Cs, 0, 0, 0);                                        \
    Cs = MFMA16(A42, b2_, Cs, 0, 0, 0);                                        \
    f4v C0 = MFMA16(A00, b0_, kz, 0, 0, 0);                                    \
    C0 = MFMA16(A01, b1_, C0, 0, 0, 0);                                        \
    C0 = MFMA16(A02, b2_, C0, 0, 0, 0);                                        \
    f4v C1 = MFMA16(A10, b0_, kz, 0, 0, 0);                                    \
    C1 = MFMA16(A11, b1_, C1, 0, 0, 0);                                        \
    C1 = MFMA16(A12, b2_, C1, 0, 0, 0);                                        \
    f4v C2 = MFMA16(A20, b0_, kz, 0, 0, 0);                                    \
    C2 = MFMA16(A21, b1_, C2, 0, 0, 0);                                        \
    C2 = MFMA16(A22, b2_, C2, 0, 0, 0);                                        \
    bool mk_ = p##B##m != 0;                                                   \
    float ninv_ = __builtin_amdgcn_rcpf(Cs[0]);                                \
    S0 = mk_ ? C0 : S0;                                                        \
    S1 = mk_ ? C1 : S1;                                                        \
    S2 = mk_ ? C2 : S2;                                                        \
    inv = mk_ ? ninv_ : inv;                                                   \
    ls += mk_ ? __logf(Cs[0]) : 0.0f;                                          \
}

__attribute__((amdgpu_flat_work_group_size(128,128), amdgpu_waves_per_eu(1,2)))
__global__ void crf_scan_kernel(
    const float* __restrict__ em,
    const float* __restrict__ start_t,
    const float* __restrict__ end_t,
    const float* __restrict__ trans,
    const int*   __restrict__ maskp,
    float*       __restrict__ z_out) {
    const int bb = blockIdx.x * 16;        // batch tile base
    const int w = threadIdx.x >> 6;        // 0 = fwd wave, 1 = bwd wave
    const bool fwd = (w == 0);
    const int lane = threadIdx.x & 63;
    const int c = lane & 15;               // batch column
    const int g = lane >> 4;               // row group

    __shared__ float shX[NTAG][17];
    __shared__ float shL[16];
    __shared__ float sh_w4[2][NTAG];

    // cooperative w4: fwd wave needs rowsum of E, bwd wave colsum of E
    if (lane < NTAG) {
        float s = 0.f;
        #pragma unroll 8
        for (int t2 = 0; t2 < NTAG; ++t2)
            s += __expf(trans[fwd ? (lane * NTAG + t2) : (t2 * NTAG + lane)]);
        sh_w4[w][lane] = s;
    }
    __syncthreads();

    // ---- constant A fragments (verified mapping from round 9):
    // fwd A=E^T (A[m][k]=E[k][m]); bwd A=E.  m = lane&15, k = 16*KT + 4*g + j.
    h4v A00, A01, A02, A10, A11, A12, A20, A21, A22, A40, A41, A42;
    {
        #define LOADA(MT, KT, DST) {                                           \
            float e_[4];                                                       \
            _Pragma("unroll") for (int j = 0; j < 4; ++j) {                    \
                int kidx_ = 16*(KT) + 4*g + j;                                 \
                int midx_ = 16*(MT) + c;                                       \
                int r_ = fwd ? kidx_ : midx_;                                  \
                int cc_ = fwd ? midx_ : kidx_;                                 \
                e_[j] = __expf(trans[r_ * NTAG + cc_]);                        \
            }                                                                  \
            DST = pk4(e_[0], e_[1], e_[2], e_[3]);                             \
        }
        #define LOADA4(KT, DST) {                                              \
            float e_[4];                                                       \
            _Pragma("unroll") for (int j = 0; j < 4; ++j)                      \
                e_[j] = sh_w4[w][16*(KT) + 4*g + j];                           \
            DST = pk4(e_[0], e_[1], e_[2], e_[3]);                             \
        }
        LOADA(0,0,A00) LOADA(0,1,A01) LOADA(0,2,A02)
        LOADA(1,0,A10) LOADA(1,1,A11) LOADA(1,2,A12)
        LOADA(2,0,A20) LOADA(2,1,A21) LOADA(2,2,A22)
        LOADA4(0,A40)  LOADA4(1,A41)  LOADA4(2,A42)
        #undef LOADA
        #undef LOADA4
    }

    const f4v kz = {0.f, 0.f, 0.f, 0.f};
    const size_t laneoff = (size_t)(bb + c) * NTAG + (size_t)g * 4;

    // ---- state
    h4v Bf0, Bf1, Bf2;        // fwd: X_hat fp16 B-fragments
    f4v S0, S1, S2;           // bwd: raw C-layout f32 state
    float inv = 1.0f;         // bwd pending scale
    float ls = 0.0f;          // accumulated log-scale

    if (fwd) {
        f4v e0 = *(const f4v*)(em + laneoff);
        f4v e1 = *(const f4v*)(em + laneoff + 16);
        f4v e2 = *(const f4v*)(em + laneoff + 32);
        float x0[4], x1[4], x2[4];
        #pragma unroll
        for (int j = 0; j < 4; ++j) {
            x0[j] = __expf(start_t[ 0 + 4*g + j] + e0[j]);
            x1[j] = __expf(start_t[16 + 4*g + j] + e1[j]);
            x2[j] = __expf(start_t[32 + 4*g + j] + e2[j]);
        }
        Bf0 = pk4(x0[0], x0[1], x0[2], x0[3]);
        Bf1 = pk4(x1[0], x1[1], x1[2], x1[3]);
        Bf2 = pk4(x2[0], x2[1], x2[2], x2[3]);
    } else {
        #pragma unroll
        for (int j = 0; j < 4; ++j) {
            S0[j] = __expf(end_t[ 0 + 4*g + j]);
            S1[j] = __expf(end_t[16 + 4*g + j]);
            S2[j] = __expf(end_t[32 + 4*g + j]);
        }
    }

    // ---- main scan: 512 iterations, 4-deep prefetch
    PFDECL(0) PFDECL(1) PFDECL(2) PFDECL(3)
    PF(0, 0) PF(1, 1) PF(2, 2) PF(3, 3)
    if (fwd) {
        #pragma unroll 1
        for (int i = 0; i < 512; i += 4) {
            STEP_F(0) PF(0, i + 4)
            STEP_F(1) PF(1, i + 5)
            STEP_F(2) PF(2, i + 6)
            STEP_F(3) PF(3, i + 7)
        }
    } else {
        #pragma unroll 1
        for (int i = 0; i < 512; i += 4) {
            STEP_B(0) PF(0, i + 4)
            STEP_B(1) PF(1, i + 5)
            STEP_B(2) PF(2, i + 6)
            STEP_B(3) PF(3, i + 7)
        }
    }

    // ---- combine:  logZ_b = lsF + lsB + log( inv_b * sum_t Xhat[t,b]*S[t,b] )
    if (fwd) {
        #pragma unroll
        for (int j = 0; j < 4; ++j) {
            shX[ 0 + 4*g + j][c] = (float)Bf0[j];
            shX[16 + 4*g + j][c] = (float)Bf1[j];
            shX[32 + 4*g + j][c] = (float)Bf2[j];
        }
        if (lane < 16) shL[lane] = ls;
    }
    __syncthreads();
    if (!fwd) {
        float d = 0.f;
        #pragma unroll
        for (int j = 0; j < 4; ++j) {
            d += S0[j] * shX[ 0 + 4*g + j][c];
            d += S1[j] * shX[16 + 4*g + j][c];
            d += S2[j] * shX[32 + 4*g + j][c];
        }
        d = colsum4(d);
        float logz = shL[c] + ls + __logf(d * inv);
        if (lane < 16) z_out[bb + lane] = logz;
    }
}

__global__ __launch_bounds__(64) void crf_num_kernel(
    const float* __restrict__ em,
    const float* __restrict__ start_t,
    const float* __restrict__ end_t,
    const float* __restrict__ trans,
    const int*   __restrict__ tags,
    const int*   __restrict__ maskp,
    float*       __restrict__ num_out) {
    const int b = blockIdx.x;
    const int lane = threadIdx.x;
    float numpart = 0.0f;
    int cnt = 0;
    #pragma unroll 4
    for (int jj = 0; jj < 16; ++jj) {
        int i = jj * 64 + lane;
        int tag_i = tags[(size_t)i * BATCH_N + b];
        int m = maskp[i * BATCH_N + b];
        cnt += (m != 0);
        if (i == 0) {
            numpart += start_t[tag_i] + em[(size_t)b * NTAG + tag_i];
        } else if (m) {
            int tag_p = tags[(size_t)(i - 1) * BATCH_N + b];
            numpart += trans[tag_p * NTAG + tag_i] +
                       em[((size_t)i * BATCH_N + b) * NTAG + tag_i];
        }
    }
    float num = wave_sum_f(numpart);
    int seq_len = wave_sum_i(cnt);
    int last_tag = tags[(size_t)(seq_len - 1) * BATCH_N + b];
    if (lane == 0) num_out[b] = num + end_t[last_tag];
}

__global__ __launch_bounds__(512) void final_reduce_kernel(
    const float* __restrict__ z, const float* __restrict__ num,
    float* __restrict__ out) {
    float x = z[threadIdx.x] - num[threadIdx.x];   // = -llh[b]
    x = wave_sum_f(x);
    __shared__ float ws[8];
    int w = threadIdx.x >> 6;
    if ((threadIdx.x & 63) == 0) ws[w] = x;
    __syncthreads();
    if (threadIdx.x == 0) {
        float t = 0.0f;
        #pragma unroll
        for (int k = 0; k < 8; ++k) t += ws[k];
        *out = t;
    }
}

extern "C" void kernel_launch(void* const* d_in, const int* in_sizes, int n_in,
                              void* d_out, int out_size, void* d_ws, size_t ws_size,
                              hipStream_t stream) {
    const float* emissions = (const float*)d_in[0];
    const float* start_t   = (const float*)d_in[1];
    const float* end_t     = (const float*)d_in[2];
    const float* trans     = (const float*)d_in[3];
    const int*   tags      = (const int*)d_in[4];
    const int*   mask      = (const int*)d_in[5];
    float* z_ws   = (float*)d_ws;            // [512]
    float* num_ws = z_ws + BATCH_N;          // [512]

    crf_scan_kernel<<<BATCH_N / 16, 128, 0, stream>>>(emissions, start_t, end_t,
                                                      trans, mask, z_ws);
    crf_num_kernel<<<BATCH_N, 64, 0, stream>>>(emissions, start_t, end_t, trans,
                                               tags, mask, num_ws);
    final_reduce_kernel<<<1, 512, 0, stream>>>(z_ws, num_ws, (float*)d_out);
}